// Round 1
// 1714.132 us; speedup vs baseline: 1.0017x; 1.0017x over previous
//
#include <hip/hip_runtime.h>

// SqRL ring gather, H = W = 512 (even), lmid = 255, Hr = 256, row width 4H = 2048.
// Ring index map (verified): i = 255-dif, el = 2*dif+1,
//   b1=i+el(=256+dif), b2=b1+2i(=766-dif), b3=b2+el(=767+dif), b4=b3+2i(=1277-dif),
//   b5=b4+el(=1278+dif), b6=b5+2i(=1788-dif), b7=b6+el(=1789+dif), wrap at 2044.
// Vertical segments are pure transposes:
//   right: j in [b2,b3) <=> |j-766|<=dif,  out[dif][j] = x[j-511][256+dif]   (j = r+511)
//   left : j in [b6,b7) <=> |j-1788|<=dif, out[dif][j] = x[2044-j][255-dif]  (j = 2044-r)
// Phase A (closed-form gather) writes everything EXCEPT vertical interiors
// (float4 where quad is clean, scalar at straddles, never touching vertical elems).
// Phase B (LDS 64x64 tiled transpose) writes exactly the vertical triangles.
// Disjoint at 4B granularity -> single launch, no ordering hazard.

#define SQRL_H 512
#define SQRL_IMG ((size_t)SQRL_H * SQRL_H)
#define SQRL_ROWW 2048
#define NB_PER_IMG 72   // 2 sides * 4 dif-tiles * 9 j-tiles

__global__ __launch_bounds__(256) void sqrl_kernel(
    const float* __restrict__ x, float* __restrict__ outf, long n4, long nB) {
    __shared__ float lds[64][65];   // pad 65: column reads conflict-free
    const long bid = blockIdx.x;

    if (bid < nB) {
        // ---------------- Phase B: triangular transpose ----------------
        const int  rem  = (int)(bid % NB_PER_IMG);
        const long img  = bid / NB_PER_IMG;
        const int  jt   = rem % 9;
        const int  dt   = (rem / 9) & 3;
        const int  side = rem / 36;          // 0 = right edge, 1 = left edge
        const int  dif0 = dt * 64;
        const int  j0   = (side == 0 ? 448 : 1472) + 64 * jt;
        const int  ctr  = (side == 0) ? 766 : 1788;

        int jmin;                             // min |j-ctr| over this j-tile
        if (j0 <= ctr && ctr < j0 + 64) jmin = 0;
        else {
            int a = j0 - ctr;        if (a < 0) a = -a;
            int b = j0 + 63 - ctr;   if (b < 0) b = -b;
            jmin = a < b ? a : b;
        }
        const int dmax = dif0 + 63;
        if (dmax < jmin) return;              // tile entirely outside triangle

        const int rlo = (side == 0) ? (j0 - 511) : (1981 - j0);
        const int clo = (side == 0) ? (256 + dif0) : (192 - dif0);
        const int rc  = (side == 0) ? 255 : 256;
        const float* __restrict__ base = x + img * SQRL_IMG;
        const int t = (int)threadIdx.x;

        // Load: rows rlo..rlo+63, cols clo..clo+63 (trimmed to triangle).
        {
            const int lr = t >> 2;
            const int q  = t & 3;
            const int r  = rlo + lr;
            if ((unsigned)r < 512u) {
                int adr = r - rc; if (adr < 0) adr = -adr;
                if (adr <= dmax) {
                    const float* rowp = base + (size_t)r * SQRL_H;
#pragma unroll
                    for (int k = 0; k < 4; ++k) {
                        const int c0 = (q + 4 * k) * 4;  // 16B-aligned (clo is 64-mult)
                        const bool need = (side == 0)
                            ? (clo + c0 + 3 >= 256 + adr)   // used cols >= 256+adr
                            : (clo + c0     <= 255 - adr);  // used cols <= 255-adr
                        if (need) {
                            const float4 v = *reinterpret_cast<const float4*>(rowp + clo + c0);
                            lds[lr][c0 + 0] = v.x;          // 2-way bank alias: free
                            lds[lr][c0 + 1] = v.y;
                            lds[lr][c0 + 2] = v.z;
                            lds[lr][c0 + 3] = v.w;
                        }
                    }
                }
            }
        }
        __syncthreads();

        // Store: lanes along j (contiguous, j0 64-aligned -> full 256B runs).
        const int jl   = t & 63;
        const int dgrp = t >> 6;
        const int j    = j0 + jl;
        int adj = j - ctr; if (adj < 0) adj = -adj;
        const int lj = (side == 0) ? jl : (63 - jl);
        float* const orow = outf + ((size_t)img * 256 + dif0) * SQRL_ROWW + j;
#pragma unroll
        for (int it = 0; it < 16; ++it) {
            const int dl = dgrp + 4 * it;
            if (dif0 + dl >= adj) {           // exactly |j-ctr| <= dif
                const int lc = (side == 0) ? dl : (63 - dl);
                orow[(size_t)dl * SQRL_ROWW] = lds[lj][lc];
            }
        }
        return;
    }

    // ---------------- Phase A: closed-form gather, verticals skipped ----------------
    const long tA = (bid - nB) * 256 + threadIdx.x;
    if (tA >= n4) return;

    const int  j4  = (int)(tA & 511);
    const long row = tA >> 9;
    const int  dif = (int)(row & 255);
    const long img = row >> 8;
    const float* __restrict__ base = x + img * SQRL_IMG;

    const int i_ = 255 - dif;
    const int el = 2 * dif + 1;
    const int b1 = i_ + el;
    const int b2 = b1 + 2 * i_;
    const int b3 = b2 + el;
    const int b4 = b3 + 2 * i_;
    const int b5 = b4 + el;
    const int b6 = b5 + 2 * i_;
    const int b7 = b6 + el;

    const int j0 = j4 * 4;
    float4 v;
    float* vp = reinterpret_cast<float*>(&v);
    unsigned vm = 0;
#pragma unroll
    for (int k = 0; k < 4; ++k) {
        const int j  = j0 + k;
        const int jj = (j >= 2044) ? (j - 2044) : j;   // tail wrap (never vertical)
        const bool vert = (jj >= b2 && jj < b3) || (jj >= b6 && jj < b7);
        if (vert) { vm |= 1u << k; vp[k] = 0.0f; continue; }  // phase B owns these
        int r, c;
        if (jj < b1)      { r = i_;       c = (jj > i_) ? jj : i_; }
        else if (jj < b3) { c = 511 - i_; int d = jj - b2; r = i_ + (d > 0 ? d : 0); }
        else if (jj < b5) { r = b1;       int d = jj - b4; c = b1 - (d > 0 ? d : 0); }
        else if (jj < b7) { c = i_;       int d = jj - b6; r = b1 - (d > 0 ? d : 0); }
        else              { r = i_;       c = i_; }
        vp[k] = base[(size_t)r * SQRL_H + c];
    }
    if (vm == 0u) {
        *reinterpret_cast<float4*>(outf + (size_t)tA * 4) = v;   // clean quad
    } else if (vm != 15u) {
#pragma unroll
        for (int k = 0; k < 4; ++k)                              // straddle: scalars only
            if (!(vm & (1u << k))) outf[(size_t)tA * 4 + k] = vp[k];
    } // vm == 15: fully vertical quad, nothing to do
}

extern "C" void kernel_launch(void* const* d_in, const int* in_sizes, int n_in,
                              void* d_out, int out_size, void* d_ws, size_t ws_size,
                              hipStream_t stream) {
    const float* x = (const float*)d_in[0];
    float* outf = (float*)d_out;
    long n4   = (long)out_size / 4;           // float4 count (same formula as passing baseline)
    long nA   = (n4 + 255) / 256;             // 262,144 phase-A blocks
    long nimg = n4 >> 17;                     // n4 / (256 rings * 512 f4/row) = 512 images
    long nB   = nimg * NB_PER_IMG;            // 36,864 phase-B blocks (B first: heavier)
    long nblocks = nA + nB;
    sqrl_kernel<<<dim3((unsigned)nblocks), dim3(256), 0, stream>>>(x, outf, n4, nB);
}

// Round 3
// 1608.349 us; speedup vs baseline: 1.0676x; 1.0658x over previous
//
#include <hip/hip_runtime.h>

// SqRL ring gather, H = W = 512 (even), lmid = 255, Hr = 256, row width 4H = 2048.
// Ring index map (verified r0/r1): i = 255-dif, el = 2*dif+1,
//   b1=256+dif, b2=766-dif, b3=767+dif, b4=1277-dif, b5=1278+dif, b6=1788-dif,
//   b7=1789+dif, seg8 ends at 2044, tail [2044,2048) wraps to p-2044.
// Out-row layout: [0,i) c_tl | [i,b1) top asc | [b1,b2) c_tr | [b2,b3) VERT-R |
//   [b3,b4) c_br | [b4,b5) bottom desc | [b5,b6) c_bl | [b6,b7) VERT-L |
//   [b7,2044) c_tl | wrap.
// Phase A: one block per (img,dif) out row; per-QUAD segment classification:
//   broadcasts = register splat (no loads), top = float4 load, bottom = 2x float2
//   reversed, verticals skipped, boundary/wrap quads take the per-element path.
// Phase B: LDS 64x64 triangular transpose (unchanged from r1, verified):
//   right: out[dif][j] = x[j-511][256+dif]; left: out[dif][j] = x[2044-j][255-dif].
// A and B are disjoint at 4B granularity -> single launch.

#define SQRL_H 512
#define SQRL_IMG ((size_t)SQRL_H * SQRL_H)
#define SQRL_ROWW 2048
#define NB_PER_IMG 72   // 2 sides * 4 dif-tiles * 9 j-tiles

typedef float f32x4 __attribute__((ext_vector_type(4)));  // native vec: NT-store OK

__global__ __launch_bounds__(256) void sqrl_kernel(
    const float* __restrict__ x, float* __restrict__ outf, long nB) {
    __shared__ float lds[64][65];   // pad 65: column reads conflict-free
    const long bid = blockIdx.x;

    if (bid < nB) {
        // ---------------- Phase B: triangular transpose (r1, verified) ----------------
        const int  rem  = (int)(bid % NB_PER_IMG);
        const long img  = bid / NB_PER_IMG;
        const int  jt   = rem % 9;
        const int  dt   = (rem / 9) & 3;
        const int  side = rem / 36;          // 0 = right edge, 1 = left edge
        const int  dif0 = dt * 64;
        const int  j0   = (side == 0 ? 448 : 1472) + 64 * jt;
        const int  ctr  = (side == 0) ? 766 : 1788;

        int jmin;
        if (j0 <= ctr && ctr < j0 + 64) jmin = 0;
        else {
            int a = j0 - ctr;        if (a < 0) a = -a;
            int b = j0 + 63 - ctr;   if (b < 0) b = -b;
            jmin = a < b ? a : b;
        }
        const int dmax = dif0 + 63;
        if (dmax < jmin) return;

        const int rlo = (side == 0) ? (j0 - 511) : (1981 - j0);
        const int clo = (side == 0) ? (256 + dif0) : (192 - dif0);
        const int rc  = (side == 0) ? 255 : 256;
        const float* __restrict__ base = x + img * SQRL_IMG;
        const int t = (int)threadIdx.x;

        {
            const int lr = t >> 2;
            const int q  = t & 3;
            const int r  = rlo + lr;
            if ((unsigned)r < 512u) {
                int adr = r - rc; if (adr < 0) adr = -adr;
                if (adr <= dmax) {
                    const float* rowp = base + (size_t)r * SQRL_H;
#pragma unroll
                    for (int k = 0; k < 4; ++k) {
                        const int c0 = (q + 4 * k) * 4;
                        const bool need = (side == 0)
                            ? (clo + c0 + 3 >= 256 + adr)
                            : (clo + c0     <= 255 - adr);
                        if (need) {
                            const f32x4 v = *reinterpret_cast<const f32x4*>(rowp + clo + c0);
                            lds[lr][c0 + 0] = v.x;
                            lds[lr][c0 + 1] = v.y;
                            lds[lr][c0 + 2] = v.z;
                            lds[lr][c0 + 3] = v.w;
                        }
                    }
                }
            }
        }
        __syncthreads();

        const int jl   = t & 63;
        const int dgrp = t >> 6;
        const int j    = j0 + jl;
        int adj = j - ctr; if (adj < 0) adj = -adj;
        const int lj = (side == 0) ? jl : (63 - jl);
        float* const orow = outf + ((size_t)img * 256 + dif0) * SQRL_ROWW + j;
#pragma unroll
        for (int it = 0; it < 16; ++it) {
            const int dl = dgrp + 4 * it;
            if (dif0 + dl >= adj) {
                const int lc = (side == 0) ? dl : (63 - dl);
                orow[(size_t)dl * SQRL_ROWW] = lds[lj][lc];
            }
        }
        return;
    }

    // ---------------- Phase A: one block per output row, per-quad fast paths ----------------
    const long rowid = bid - nB;             // img*256 + dif
    const int  dif = (int)(rowid & 255);
    const long img = rowid >> 8;
    const float* __restrict__ base = x + img * SQRL_IMG;
    float* __restrict__ orow = outf + (size_t)rowid * SQRL_ROWW;

    const int i_ = 255 - dif;
    const int b1 = 256 + dif;                // == i+el == 511-i
    const int b2 = 766 - dif,  b3 = 767 + dif;
    const int b4 = 1277 - dif, b5 = 1278 + dif;
    const int b6 = 1788 - dif, b7 = 1789 + dif;

    const float c_tl = base[i_ * 512 + i_];
    const float c_tr = base[i_ * 512 + b1];
    const float c_br = base[b1 * 512 + b1];
    const float c_bl = base[b1 * 512 + i_];
    const float* __restrict__ toprow = base + i_ * 512;
    const float* __restrict__ botrow = base + b1 * 512;

    const int t = (int)threadIdx.x;
#pragma unroll
    for (int h = 0; h < 2; ++h) {
        const int p0 = (t + 256 * h) * 4;    // quad start position, 16B aligned

        // segment of a position: 0 tl | 1 top | 2 tr | 3 VERT | 4 br | 5 bot |
        //                        6 bl | 7 VERT | 8 tl | 9 wrap
        auto seg = [&](int p) -> int {
            if (p < i_)   return 0;
            if (p < b1)   return 1;
            if (p < b2)   return 2;
            if (p < b3)   return 3;
            if (p < b4)   return 4;
            if (p < b5)   return 5;
            if (p < b6)   return 6;
            if (p < b7)   return 7;
            if (p < 2044) return 8;
            return 9;
        };
        const int sA = seg(p0), sB = seg(p0 + 3);

        if (sA == sB && sA != 9) {
            if (sA == 3 || sA == 7) continue;          // vertical: phase B owns
            f32x4 v;
            if (sA == 1) {
                v = *reinterpret_cast<const f32x4*>(toprow + p0);         // aligned
            } else if (sA == 5) {
                const int a0 = b1 - (p0 - b4);         // src col of p0; a0 % 4 == 1
                const float2 lo = *reinterpret_cast<const float2*>(botrow + a0 - 3);
                const float2 hi = *reinterpret_cast<const float2*>(botrow + a0 - 1);
                v.x = hi.y; v.y = hi.x; v.z = lo.y; v.w = lo.x;           // reversed
            } else {
                const float cv = (sA == 2) ? c_tr : (sA == 4) ? c_br
                               : (sA == 6) ? c_bl : c_tl;                  // 0/8 -> tl
                v.x = cv; v.y = cv; v.z = cv; v.w = cv;
            }
            __builtin_nontemporal_store(v, reinterpret_cast<f32x4*>(orow + p0));
        } else {
            // boundary or wrap quad: per-element (rare, <=10 quads per row)
            float vals[4]; unsigned vm = 0;
#pragma unroll
            for (int k = 0; k < 4; ++k) {
                const int p = p0 + k;
                float val;
                if (p < i_)        val = c_tl;
                else if (p < b1)   val = toprow[p];
                else if (p < b2)   val = c_tr;
                else if (p < b3)   { vm |= 1u << k; val = 0.0f; }
                else if (p < b4)   val = c_br;
                else if (p < b5)   val = botrow[b1 - (p - b4)];
                else if (p < b6)   val = c_bl;
                else if (p < b7)   { vm |= 1u << k; val = 0.0f; }
                else if (p < 2044) val = c_tl;
                else { const int p2 = p - 2044; val = (p2 < i_) ? c_tl : toprow[p2]; }
                vals[k] = val;
            }
            if (vm == 0u) {
                f32x4 v; v.x = vals[0]; v.y = vals[1]; v.z = vals[2]; v.w = vals[3];
                __builtin_nontemporal_store(v, reinterpret_cast<f32x4*>(orow + p0));
            } else if (vm != 15u) {
#pragma unroll
                for (int k = 0; k < 4; ++k)
                    if (!(vm & (1u << k))) orow[p0 + k] = vals[k];
            }
        }
    }
}

extern "C" void kernel_launch(void* const* d_in, const int* in_sizes, int n_in,
                              void* d_out, int out_size, void* d_ws, size_t ws_size,
                              hipStream_t stream) {
    const float* x = (const float*)d_in[0];
    float* outf = (float*)d_out;
    long n4   = (long)out_size / 4;           // float4 count
    long nimg = n4 >> 17;                     // 512 images
    long nB   = nimg * NB_PER_IMG;            // 36,864 transpose blocks (first)
    long nA   = nimg * 256;                   // 131,072 row blocks
    long nblocks = nB + nA;
    sqrl_kernel<<<dim3((unsigned)nblocks), dim3(256), 0, stream>>>(x, outf, nB);
}